// Round 4
// baseline (307.619 us; speedup 1.0000x reference)
//
#include <hip/hip_runtime.h>
#include <math.h>

// WaveLM: logits[b,t,v] = sum_{t'<t} g(id[b,t'], v)
// g(u,v) = 2 * sum_{i,j in 1..H} (A_u/i^dec)(A_v/j^dec) * sinc(2*(f_u*i - f_v*j))
// sinc(2d) = sin(2*pi*d)/(2*pi*d), sinc(0)=1
//
// R4: - per-vocab table (sin/cos harmonics, w=A*h^-dec, f*h) precomputed once
//     - main kernel: block = 8 consecutive tokens x 512-v tile; v-side setup
//       amortized over 8 tokens; u-side via uniform (scalar) table reads
//     - hot loop in ext_vector_type(2) float -> v_pk_{fma,mul,add}_f32
//     - unguarded batch inversion; rare lanes (exact-zero d / under/overflow)
//       redo a guarded scalar path per token
//     - scan: non-atomic 2-pass segmented scan (no atomics, no XCD thrash)

typedef float v2f __attribute__((ext_vector_type(2)));

constexpr int cB = 4, cT = 512, cV = 8000, cH = 7;
constexpr int SEG = 8, SEGLEN = 64;     // cT = SEG*SEGLEN
constexpr int GT  = 8;                  // tokens per block in wavelm_g
constexpr int REC = 32;                 // floats per vocab record (128 B)
// record: [0..6]=sin(2pi f h), [7..13]=cos(2pi f h), [14..20]=A*h^-dec, [21..27]=f*h

__global__ __launch_bounds__(256) void wavelm_tab(
    const float* __restrict__ freq, const float* __restrict__ amp,
    const float* __restrict__ decay_p, float* __restrict__ tab)
{
    const int v = blockIdx.x * 256 + threadIdx.x;
    if (v >= cV) return;
    const float decay = decay_p[0];
    const float f = freq[v], A = amp[v];
    const float p2 = __builtin_amdgcn_exp2f(-decay);
    const float p3 = __builtin_amdgcn_exp2f(-decay * 1.5849625007f);
    const float p5 = __builtin_amdgcn_exp2f(-decay * 2.3219280949f);
    const float p7 = __builtin_amdgcn_exp2f(-decay * 2.8073549221f);
    const float rp[7] = {1.f, p2, p3, p2*p2, p5, p2*p3, p7};
    const float xr = f - rintf(f);
    const float s1 = __builtin_amdgcn_sinf(xr);
    const float c1 = __builtin_amdgcn_cosf(xr);
    float* r = tab + (size_t)v * REC;
    float s = s1, c = c1;
#pragma unroll
    for (int k = 0; k < cH; ++k) {
        if (k) { const float sp = s, cp = c;
                 s = fmaf(sp, c1,  cp * s1);
                 c = fmaf(cp, c1, -(sp * s1)); }
        r[k]      = s;
        r[7 + k]  = c;
        r[14 + k] = A * rp[k];
        r[21 + k] = f * (float)(k + 1);
    }
    r[28] = 0.f; r[29] = 0.f; r[30] = 0.f; r[31] = 0.f;
}

__global__ __launch_bounds__(256) void wavelm_g(
    const int* __restrict__ ids, const float* __restrict__ tab,
    float* __restrict__ out)
{
    const int bt0 = blockIdx.y * GT;                  // first token of this block
    const int vh  = blockIdx.x * 256 + threadIdx.x;   // v-pair index
    const int v0  = vh * 2;
    const bool valid = (v0 < cV);
    const int vv  = valid ? v0 : 0;

    // ---- v-side setup, ONCE per thread (amortized over GT tokens) ----
    float rec0[28], rec1[28];
    {
        const float4* r0 = (const float4*)(tab + (size_t)vv * REC);
        const float4* r1 = (const float4*)(tab + (size_t)(vv + 1) * REC);
#pragma unroll
        for (int q = 0; q < 7; ++q) {
            ((float4*)rec0)[q] = r0[q];
            ((float4*)rec1)[q] = r1[q];
        }
    }
    const float INV2PI = 0.15915494309189535f;
    v2f bang[cH], sBw[cH], cBw[cH], wV[cH];
#pragma unroll
    for (int j = 0; j < cH; ++j) {
        v2f w;  w.x = rec0[14+j];         w.y = rec1[14+j];
        v2f ws; ws.x = w.x * INV2PI;      ws.y = w.y * INV2PI;
        v2f s;  s.x = rec0[j];            s.y = rec1[j];
        v2f c;  c.x = rec0[7+j];          c.y = rec1[7+j];
        wV[j]  = w;
        sBw[j] = s * ws;
        cBw[j] = c * ws;
        bang[j].x = rec0[21+j];           bang[j].y = rec1[21+j];
    }

    // ---- token loop ----
    for (int g = 0; g < GT; ++g) {
        const int bt = bt0 + g;
        const int id = __builtin_amdgcn_readfirstlane(ids[bt]);
        const float* ur = tab + (size_t)id * REC;
        float sA[cH], cA[cH], wA[cH], au[cH];
#pragma unroll
        for (int i = 0; i < cH; ++i) {
            sA[i] = ur[i]; cA[i] = ur[7+i]; wA[i] = ur[14+i]; au[i] = ur[21+i];
        }

        v2f acc = (v2f)0.f;
        float mn = 3.0e38f, mx = 0.0f;
#pragma unroll
        for (int i = 0; i < cH; ++i) {
            v2f ai;  ai  = (v2f)au[i];
            v2f d[cH], p[cH];
#pragma unroll
            for (int j = 0; j < cH; ++j) d[j] = ai - bang[j];
            p[0] = d[0];
#pragma unroll
            for (int j = 1; j < cH; ++j) p[j] = p[j-1] * d[j];
            const float ptot = p[6].x * p[6].y;
            mn = fminf(mn, fminf(fabsf(p[6].x), fabsf(p[6].y)));
            mn = fminf(mn, fabsf(ptot));
            mx = fmaxf(mx, fabsf(ptot));
            const float rt = __builtin_amdgcn_rcpf(ptot);
            v2f r;  r.x = rt * p[6].y;  r.y = rt * p[6].x;
            v2f inv[cH];
#pragma unroll
            for (int j = cH - 1; j >= 1; --j) { inv[j] = r * p[j-1]; r = r * d[j]; }
            inv[0] = r;

            v2f sAi = (v2f)sA[i];
            v2f cAi = (v2f)cA[i];
            v2f acci = (v2f)0.f;
#pragma unroll
            for (int j = 0; j < cH; ++j) {
                v2f m  = cAi * sBw[j];
                v2f sn = __builtin_elementwise_fma(sAi, cBw[j], -m);
                acci   = __builtin_elementwise_fma(sn, inv[j], acci);
            }
            acc = __builtin_elementwise_fma((v2f)wA[i], acci, acc);
        }

        // rare guarded path: exact-zero d (v==id), underflow, overflow
        if (mn < 1e-37f || mx > 1e37f) {
            acc = (v2f)0.f;
#pragma unroll
            for (int i = 0; i < cH; ++i) {
                float ax = 0.f, ay = 0.f;
#pragma unroll
                for (int j = 0; j < cH; ++j) {
                    const float dx = au[i] - bang[j].x;
                    const float dy = au[i] - bang[j].y;
                    const float snx = fmaf(sA[i], cBw[j].x, -(cA[i] * sBw[j].x));
                    const float sny = fmaf(sA[i], cBw[j].y, -(cA[i] * sBw[j].y));
                    float qx = snx * __builtin_amdgcn_rcpf(dx);
                    float qy = sny * __builtin_amdgcn_rcpf(dy);
                    qx = (dx == 0.f) ? wV[j].x : qx;
                    qy = (dy == 0.f) ? wV[j].y : qy;
                    ax += qx;  ay += qy;
                }
                acc.x = fmaf(wA[i], ax, acc.x);
                acc.y = fmaf(wA[i], ay, acc.y);
            }
        }

        if (valid) {
            v2f res = 2.0f * acc;
            *(v2f*)(out + (size_t)bt * cV + v0) = res;
        }
    }
}

// pass 1: per-(b,seg,v) segment sums
__global__ __launch_bounds__(256) void wavelm_seg(
    const float* __restrict__ out, float* __restrict__ segsum)
{
    const int v = blockIdx.x * 256 + threadIdx.x;
    if (v >= cV) return;
    const int bs = blockIdx.y, b = bs >> 3, seg = bs & (SEG - 1);
    const float* p = out + ((size_t)b * cT + (size_t)seg * SEGLEN) * cV + v;
    float a0 = 0.f, a1 = 0.f, a2 = 0.f, a3 = 0.f;
#pragma unroll
    for (int k = 0; k < SEGLEN; k += 4) {
        a0 += p[(size_t)(k+0) * cV];
        a1 += p[(size_t)(k+1) * cV];
        a2 += p[(size_t)(k+2) * cV];
        a3 += p[(size_t)(k+3) * cV];
    }
    segsum[(size_t)bs * cV + v] = (a0 + a1) + (a2 + a3);
}

// pass 2: base from segsum prefix + in-place local shifted scan
__global__ __launch_bounds__(256) void wavelm_scan2(
    float* __restrict__ out, const float* __restrict__ segsum)
{
    const int v = blockIdx.x * 256 + threadIdx.x;
    if (v >= cV) return;
    const int bs = blockIdx.y, b = bs >> 3, seg = bs & (SEG - 1);
    float base = 0.f;
    for (int sp = 0; sp < seg; ++sp)
        base += segsum[(size_t)(b * SEG + sp) * cV + v];
    float* p = out + ((size_t)b * cT + (size_t)seg * SEGLEN) * cV + v;
    float acc = base;
#pragma unroll 8
    for (int k = 0; k < SEGLEN; ++k) {
        const float c = p[(size_t)k * cV];
        p[(size_t)k * cV] = acc;
        acc += c;
    }
}

// fallback full-chain scan (ws too small for segsum)
__global__ __launch_bounds__(256) void wavelm_scan(float* __restrict__ out)
{
    const int g = blockIdx.x * blockDim.x + threadIdx.x;
    if (g >= cB * cV) return;
    const int b = g / cV;
    const int v = g - b * cV;
    float* p = out + (size_t)b * cT * cV + v;
    float acc = 0.f;
#pragma unroll 8
    for (int t = 0; t < cT; ++t) {
        const float c = p[(size_t)t * cV];
        p[(size_t)t * cV] = acc;
        acc += c;
    }
}

extern "C" void kernel_launch(void* const* d_in, const int* in_sizes, int n_in,
                              void* d_out, int out_size, void* d_ws, size_t ws_size,
                              hipStream_t stream)
{
    const int*   ids  = (const int*)d_in[0];
    const float* freq = (const float*)d_in[1];
    const float* amp  = (const float*)d_in[2];
    const float* dec  = (const float*)d_in[3];
    float* out = (float*)d_out;
    float* tab = (float*)d_ws;                       // 8000*32*4 = 1,024,000 B
    float* segsum = tab + (size_t)cV * REC;          // +4*8*8000*4 = 1,024,000 B

    const size_t tab_b = (size_t)cV * REC * sizeof(float);
    const size_t seg_b = (size_t)cB * SEG * cV * sizeof(float);
    const int use_seg = (ws_size >= tab_b + seg_b) ? 1 : 0;

    wavelm_tab<<<(cV + 255) / 256, 256, 0, stream>>>(freq, amp, dec, tab);

    dim3 grid((cV / 2 + 255) / 256, cB * cT / GT);   // 16 x 256
    wavelm_g<<<grid, dim3(256), 0, stream>>>(ids, tab, out);

    if (use_seg) {
        dim3 sg((cV + 255) / 256, cB * SEG);         // 32 x 32
        wavelm_seg<<<sg, dim3(256), 0, stream>>>(out, segsum);
        wavelm_scan2<<<sg, dim3(256), 0, stream>>>(out, segsum);
    } else {
        const int nchains = cB * cV;
        wavelm_scan<<<(nchains + 255) / 256, dim3(256), 0, stream>>>(out);
    }
}

// Round 5
// 225.091 us; speedup vs baseline: 1.3666x; 1.3666x over previous
//
#include <hip/hip_runtime.h>
#include <math.h>

// WaveLM: logits[b,t,v] = sum_{t'<t} g(id[b,t'], v)
// g(u,v) = 2 * sum_{i,j in 1..H} (A_u/i^dec)(A_v/j^dec) * sinc(2*(f_u*i - f_v*j))
// sinc(2d) = sin(2*pi*d)/(2*pi*d), sinc(0)=1
//
// R5: - SoA per-vocab table (28 planes of cV): sin/cos(2pi f h), w=A*h^-dec, f*h
//     - main kernel: 2 v's per thread, GT=4 tokens per block, v-side setup
//       amortized; u-side via wave-uniform scalar loads
//     - hot loop forced to packed fp32 via inline asm v_pk_{add,mul,fma}_f32
//       (compiler does NOT auto-form these; R4 proved ext_vector scalarizes)
//     - unguarded batch inversion (1 rcp per 14 divisors); rare lanes
//       (exact-zero d / under/overflow) redo a guarded scalar path
//     - scan: non-atomic 2-pass segmented scan, runtime segment count

typedef float v2f __attribute__((ext_vector_type(2)));

constexpr int cB = 4, cT = 512, cV = 8000, cH = 7;
constexpr int GT = 4;                 // tokens per wavelm_g block
constexpr int NPLANE = 28;            // table planes

__device__ __forceinline__ v2f pk_add(v2f a, v2f b) {
    v2f d; asm("v_pk_add_f32 %0, %1, %2" : "=v"(d) : "v"(a), "v"(b)); return d;
}
__device__ __forceinline__ v2f pk_mul(v2f a, v2f b) {
    v2f d; asm("v_pk_mul_f32 %0, %1, %2" : "=v"(d) : "v"(a), "v"(b)); return d;
}
__device__ __forceinline__ v2f pk_fma(v2f a, v2f b, v2f c) {
    v2f d; asm("v_pk_fma_f32 %0, %1, %2, %3" : "=v"(d) : "v"(a), "v"(b), "v"(c));
    return d;
}

__global__ __launch_bounds__(256) void wavelm_tab(
    const float* __restrict__ freq, const float* __restrict__ amp,
    const float* __restrict__ decay_p, float* __restrict__ tab)
{
    const int v = blockIdx.x * 256 + threadIdx.x;
    if (v >= cV) return;
    const float decay = decay_p[0];
    const float f = freq[v], A = amp[v];
    const float p2 = __builtin_amdgcn_exp2f(-decay);
    const float p3 = __builtin_amdgcn_exp2f(-decay * 1.5849625007f);
    const float p5 = __builtin_amdgcn_exp2f(-decay * 2.3219280949f);
    const float p7 = __builtin_amdgcn_exp2f(-decay * 2.8073549221f);
    const float rp[7] = {1.f, p2, p3, p2*p2, p5, p2*p3, p7};
    const float xr = f - rintf(f);
    const float s1 = __builtin_amdgcn_sinf(xr);
    const float c1 = __builtin_amdgcn_cosf(xr);
    float s = s1, c = c1;
#pragma unroll
    for (int k = 0; k < cH; ++k) {
        if (k) { const float sp = s, cp = c;
                 s = fmaf(sp, c1,  cp * s1);
                 c = fmaf(cp, c1, -(sp * s1)); }
        tab[(size_t)k * cV + v]        = s;
        tab[(size_t)(7 + k) * cV + v]  = c;
        tab[(size_t)(14 + k) * cV + v] = A * rp[k];
        tab[(size_t)(21 + k) * cV + v] = f * (float)(k + 1);
    }
}

__global__ __launch_bounds__(256) void wavelm_g(
    const int* __restrict__ ids, const float* __restrict__ tab,
    float* __restrict__ out)
{
    const int bt0 = blockIdx.y * GT;
    const int vh  = blockIdx.x * 256 + threadIdx.x;     // v-pair index
    const bool valid = (vh * 2 < cV);
    const int vc = valid ? vh : 0;

    // ---- v-side setup once, amortized over GT tokens ----
    const v2f* tp = (const v2f*)tab;                    // plane k: k*(cV/2)+vc
    v2f nb[cH], sBw[cH], cBw[cH];
#pragma unroll
    for (int j = 0; j < cH; ++j) {
        const v2f s = tp[(size_t)j * (cV/2) + vc];
        const v2f c = tp[(size_t)(7 + j) * (cV/2) + vc];
        const v2f w = tp[(size_t)(14 + j) * (cV/2) + vc];
        const v2f a = tp[(size_t)(21 + j) * (cV/2) + vc];
        const v2f ws = w * 0.15915494309189535f;        // w/(2pi)
        sBw[j] = s * ws;
        cBw[j] = c * ws;
        nb[j].x = -a.x;  nb[j].y = -a.y;                // negated: d = aU + nb
    }

    for (int g = 0; g < GT; ++g) {
        const int bt = bt0 + g;
        const int id = ids[bt];                         // wave-uniform -> s_load
        float sA[cH], cA[cH], wA[cH], aU[cH];
#pragma unroll
        for (int i = 0; i < cH; ++i) {
            sA[i] = tab[(size_t)i * cV + id];
            cA[i] = tab[(size_t)(7 + i) * cV + id];
            wA[i] = tab[(size_t)(14 + i) * cV + id];
            aU[i] = tab[(size_t)(21 + i) * cV + id];
        }

        float accx = 0.f, accy = 0.f;
        float mn = 3.0e38f, mx = 0.0f;
#pragma unroll
        for (int i = 0; i < cH; ++i) {
            v2f ai;  ai.x = aU[i];  ai.y = aU[i];
            v2f d[cH], p[cH];
#pragma unroll
            for (int j = 0; j < cH; ++j) d[j] = pk_add(ai, nb[j]);
            p[0] = d[0];
#pragma unroll
            for (int j = 1; j < cH; ++j) p[j] = pk_mul(p[j-1], d[j]);
            const float ptot = p[6].x * p[6].y;
            mn = fminf(mn, fminf(fabsf(p[6].x), fabsf(p[6].y)));
            mn = fminf(mn, fabsf(ptot));
            mx = fmaxf(mx, fabsf(ptot));
            const float rt = __builtin_amdgcn_rcpf(ptot);
            v2f r;  r.x = rt * p[6].y;  r.y = rt * p[6].x;   // 1/p6 per comp
            v2f accS = (v2f)0.f, accC = (v2f)0.f;
#pragma unroll
            for (int j = cH - 1; j >= 1; --j) {
                const v2f inv = pk_mul(r, p[j-1]);
                accS = pk_fma(cBw[j], inv, accS);
                accC = pk_fma(sBw[j], inv, accC);
                r = pk_mul(r, d[j]);
            }
            accS = pk_fma(cBw[0], r, accS);
            accC = pk_fma(sBw[0], r, accC);
            // sum_j sn_j*inv_j = sA_i*accS - cA_i*accC  (per component)
            const float tx = fmaf(sA[i], accS.x, -(cA[i] * accC.x));
            const float ty = fmaf(sA[i], accS.y, -(cA[i] * accC.y));
            accx = fmaf(wA[i], tx, accx);
            accy = fmaf(wA[i], ty, accy);
        }

        // rare guarded path: exact-zero d (v==id), underflow, overflow
        if (mn < 1e-37f || mx > 1e37f) {
            accx = 0.f;  accy = 0.f;
#pragma unroll
            for (int i = 0; i < cH; ++i) {
                float ax = 0.f, ay = 0.f;
#pragma unroll
                for (int j = 0; j < cH; ++j) {
                    const v2f w = tp[(size_t)(14 + j) * (cV/2) + vc];
                    const float dx = aU[i] + nb[j].x;
                    const float dy = aU[i] + nb[j].y;
                    const float snx = fmaf(sA[i], cBw[j].x, -(cA[i] * sBw[j].x));
                    const float sny = fmaf(sA[i], cBw[j].y, -(cA[i] * sBw[j].y));
                    float qx = snx * __builtin_amdgcn_rcpf(dx);
                    float qy = sny * __builtin_amdgcn_rcpf(dy);
                    qx = (dx == 0.f) ? w.x : qx;
                    qy = (dy == 0.f) ? w.y : qy;
                    ax += qx;  ay += qy;
                }
                accx = fmaf(wA[i], ax, accx);
                accy = fmaf(wA[i], ay, accy);
            }
        }

        if (valid) {
            v2f res;  res.x = 2.f * accx;  res.y = 2.f * accy;
            *(v2f*)(out + (size_t)bt * cV + (size_t)vh * 2) = res;
        }
    }
}

// pass 1: per-(b,seg,v) segment sums. nseg runtime (power of 2), seglen=cT/nseg
__global__ __launch_bounds__(256) void wavelm_seg(
    const float* __restrict__ out, float* __restrict__ segsum,
    int lgseg, int seglen)
{
    const int v = blockIdx.x * 256 + threadIdx.x;
    if (v >= cV) return;
    const int bs = blockIdx.y;
    const int b = bs >> lgseg, seg = bs & ((1 << lgseg) - 1);
    const float* p = out + ((size_t)b * cT + (size_t)seg * seglen) * cV + v;
    float a0 = 0.f, a1 = 0.f, a2 = 0.f, a3 = 0.f;
    for (int k = 0; k < seglen; k += 4) {
        a0 += p[(size_t)(k+0) * cV];
        a1 += p[(size_t)(k+1) * cV];
        a2 += p[(size_t)(k+2) * cV];
        a3 += p[(size_t)(k+3) * cV];
    }
    segsum[(size_t)bs * cV + v] = (a0 + a1) + (a2 + a3);
}

// pass 2: base = prefix of segment sums; in-place local shifted scan
__global__ __launch_bounds__(256) void wavelm_scan2(
    float* __restrict__ out, const float* __restrict__ segsum,
    int lgseg, int seglen)
{
    const int v = blockIdx.x * 256 + threadIdx.x;
    if (v >= cV) return;
    const int bs = blockIdx.y;
    const int b = bs >> lgseg, seg = bs & ((1 << lgseg) - 1);
    const int nseg = 1 << lgseg;
    float base = 0.f;
    for (int sp = 0; sp < seg; ++sp)
        base += segsum[(size_t)(b * nseg + sp) * cV + v];
    float* p = out + ((size_t)b * cT + (size_t)seg * seglen) * cV + v;
    float acc = base;
#pragma unroll 8
    for (int k = 0; k < seglen; ++k) {
        const float c = p[(size_t)k * cV];
        p[(size_t)k * cV] = acc;
        acc += c;
    }
}

// fallback full-chain scan (ws too small for segsum)
__global__ __launch_bounds__(256) void wavelm_scan(float* __restrict__ out)
{
    const int g = blockIdx.x * blockDim.x + threadIdx.x;
    if (g >= cB * cV) return;
    const int b = g / cV;
    const int v = g - b * cV;
    float* p = out + (size_t)b * cT * cV + v;
    float acc = 0.f;
#pragma unroll 8
    for (int t = 0; t < cT; ++t) {
        const float c = p[(size_t)t * cV];
        p[(size_t)t * cV] = acc;
        acc += c;
    }
}

extern "C" void kernel_launch(void* const* d_in, const int* in_sizes, int n_in,
                              void* d_out, int out_size, void* d_ws, size_t ws_size,
                              hipStream_t stream)
{
    const int*   ids  = (const int*)d_in[0];
    const float* freq = (const float*)d_in[1];
    const float* amp  = (const float*)d_in[2];
    const float* dec  = (const float*)d_in[3];
    float* out = (float*)d_out;
    float* tab = (float*)d_ws;                           // 28*8000*4 = 896 KB
    float* segsum = tab + (size_t)NPLANE * cV;

    const size_t tab_b = (size_t)NPLANE * cV * sizeof(float);
    int lgseg = 4;                                       // prefer 16 segments
    while (lgseg > 0 &&
           tab_b + ((size_t)cB << lgseg) * cV * sizeof(float) > ws_size)
        --lgseg;
    const int use_seg =
        (lgseg > 0 &&
         tab_b + ((size_t)cB << lgseg) * cV * sizeof(float) <= ws_size) ? 1 : 0;

    wavelm_tab<<<(cV + 255) / 256, 256, 0, stream>>>(freq, amp, dec, tab);

    dim3 grid((cV / 2 + 255) / 256, cB * cT / GT);       // 16 x 512
    wavelm_g<<<grid, dim3(256), 0, stream>>>(ids, tab, out);

    if (use_seg) {
        const int nseg = 1 << lgseg;
        const int seglen = cT / nseg;
        dim3 sg((cV + 255) / 256, cB * nseg);
        wavelm_seg<<<sg, dim3(256), 0, stream>>>(out, segsum, lgseg, seglen);
        wavelm_scan2<<<sg, dim3(256), 0, stream>>>(out, segsum, lgseg, seglen);
    } else {
        const int nchains = cB * cV;
        wavelm_scan<<<(nchains + 255) / 256, dim3(256), 0, stream>>>(out);
    }
}